// Round 4
// baseline (162.524 us; speedup 1.0000x reference)
//
#include <hip/hip_runtime.h>
#include <math.h>

// Problem constants (fixed by setup_inputs)
#define NB 8
#define NC 256
#define NH 128
#define NW 128
#define HW (NH*NW)        // 16384
#define NP 64
#define NK 2
#define PXB 64            // pixels per block
#define PW 16             // prototypes per wave (4 waves cover NP=64)
#define CCH 16            // channels per LDS chunk
#define NCHUNK (NC/CCH)   // 16

// Workspace float layout (centers plain [p][c])
#define WS_CENTERS 0
#define WS_PSQ     (NP*NC)
#define WS_U       (WS_PSQ + NP)              // [p][k]
#define WS_AL      (WS_U + NP*NK)
#define WS_G2      (WS_AL + NP)

__global__ __launch_bounds__(64) void geo_precompute(
    const float* __restrict__ cm,        // (P,K)
    const float* __restrict__ alpha,     // (P,1)
    const float* __restrict__ gamma_,    // (P,1)
    const float* __restrict__ centers,   // (P,C)
    const float* __restrict__ geo,       // (P,1)
    float* __restrict__ ws)
{
    const int p = threadIdx.x;
    if (p >= NP) return;
    float s = 0.f;
    #pragma unroll
    for (int i = 0; i < NP; ++i) s += geo[i];
    const float scale = 1.0f + 0.1f * tanhf(s * (1.0f / NP));

    float psq = 0.f;
    for (int c = 0; c < NC; ++c) {
        float v = centers[p*NC + c] * scale;
        ws[WS_CENTERS + p*NC + c] = v;
        psq += v * v;
    }
    ws[WS_PSQ + p] = psq;

    float b0 = cm[p*NK+0]; b0 *= b0;
    float b1 = cm[p*NK+1]; b1 *= b1;
    const float bs = b0 + b1;
    ws[WS_U + p*NK+0] = b0 / bs;
    ws[WS_U + p*NK+1] = b1 / bs;
    ws[WS_AL + p] = 0.99f / (1.0f + expf(-alpha[p]));
    ws[WS_G2 + p] = gamma_[p] * gamma_[p];
}

// Block = 256 threads (4 waves), owns 64 consecutive pixels (same image b).
// feats staged chunk-by-chunk (16 channels) into double-buffered LDS, one
// barrier per chunk. Wave w computes prototypes [16w,16w+16) -> acc[16]/thread.
// The 16 KB staging buffer is reused as the s_act exchange buffer at the end.
__global__ __launch_bounds__(256) void geo_main(
    const float* __restrict__ feats,     // (B,C,H,W)
    const float* __restrict__ ws,
    float* __restrict__ out)             // (B,3,H,W)
{
    __shared__ float sMem[NP*PXB];       // 16 KiB, dual-purpose
    float (*sF)[CCH][PXB] = (float(*)[CCH][PXB])sMem;   // [2][16][64] staging
    float (*sS)[PXB]      = (float(*)[PXB])sMem;        // [64][64] s_act

    const int tid  = threadIdx.x;
    const int lane = tid & 63;
    const int wu   = __builtin_amdgcn_readfirstlane(tid >> 6);  // wave id

    const int pix0 = blockIdx.x * PXB;
    const int b    = pix0 >> 14;
    const int hw0  = pix0 & (HW - 1);
    const float* __restrict__ fpB = feats + (size_t)b * NC * HW + hw0;

    // staging coords: thread t loads channel (t>>4) of the chunk, pixels 4*(t&15)..+3
    const int sc = tid >> 4;
    const int sp = (tid & 15) * 4;

    float acc[PW];
    #pragma unroll
    for (int j = 0; j < PW; ++j) acc[j] = 0.f;
    float xsq = 0.f;

    const float* __restrict__ cen = ws + WS_CENTERS + (wu * PW) * NC;

    // prologue: stage chunk 0
    {
        const float4 rf0 = *(const float4*)&fpB[(size_t)sc * HW + sp];
        *(float4*)&sF[0][sc][sp] = rf0;
    }
    __syncthreads();

    #pragma unroll 1
    for (int i = 0; i < NCHUNK; ++i) {
        const int cur = i & 1;

        // issue next chunk's global load early (covers ~500cy under the FMAs)
        float4 rf;
        if (i + 1 < NCHUNK)
            rf = *(const float4*)&fpB[(size_t)((i+1)*CCH + sc) * HW + sp];

        // compute chunk i from sF[cur]
        const int c0 = i * CCH;
        float f[CCH];
        #pragma unroll
        for (int cc = 0; cc < CCH; ++cc) f[cc] = sF[cur][cc][lane];
        #pragma unroll
        for (int cc = 0; cc < CCH; ++cc) xsq += f[cc] * f[cc];
        #pragma unroll
        for (int j = 0; j < PW; ++j) {
            float a = acc[j];
            #pragma unroll
            for (int cc = 0; cc < CCH; ++cc)
                a += f[cc] * cen[j*NC + c0 + cc];   // centers via scalar loads
            acc[j] = a;
        }

        // write next chunk into the other buffer; one barrier per chunk
        if (i + 1 < NCHUNK)
            *(float4*)&sF[cur ^ 1][sc][sp] = rf;
        __syncthreads();
    }

    // finish s_act for this wave's 16 prototypes (exp spread over 4 waves)
    {
        const float* __restrict__ psq = ws + WS_PSQ;
        const float* __restrict__ al  = ws + WS_AL;
        const float* __restrict__ g2  = ws + WS_G2;
        float sv[PW];
        #pragma unroll
        for (int j = 0; j < PW; ++j) {
            const int p = wu * PW + j;
            const float d = 0.5f * (xsq - 2.f * acc[j] + psq[p]);
            sv[j] = al[p] * __expf(-g2[p] * d);
        }
        __syncthreads();   // staging reads done before overlay reuse
        #pragma unroll
        for (int j = 0; j < PW; ++j)
            sS[wu * PW + j][lane] = sv[j];
    }
    __syncthreads();

    // wave 0: sequential evidential scan per pixel (64 steps, registers only)
    if (tid < PXB) {
        const float* __restrict__ U = ws + WS_U;
        float ms0 = 0.f, ms1 = 0.f, mt = 1.f;
        #pragma unroll
        for (int p = 0; p < NP; ++p) {
            const float s   = sS[p][tid];
            const float mth = 1.f - s;
            const float m0  = s * U[2*p+0];
            const float m1  = s * U[2*p+1];
            ms0 = ms0 * (m0 + mth) + m0 * mt;
            ms1 = ms1 * (m1 + mth) + m1 * mt;
            mt *= mth;
        }
        const float inv = 1.f / (ms0 + ms1 + mt + 1e-12f);
        float* __restrict__ op = out + (size_t)b * 3 * HW + hw0 + tid;
        op[0*HW] = ms0 * inv;
        op[1*HW] = ms1 * inv;
        op[2*HW] = mt  * inv;
    }
}

extern "C" void kernel_launch(void* const* d_in, const int* in_sizes, int n_in,
                              void* d_out, int out_size, void* d_ws, size_t ws_size,
                              hipStream_t stream) {
    const float* feats   = (const float*)d_in[0];
    // d_in[1] = geo_context (unused by reference)
    const float* cm      = (const float*)d_in[2];
    const float* alpha   = (const float*)d_in[3];
    const float* gamma_  = (const float*)d_in[4];
    const float* centers = (const float*)d_in[5];
    const float* geo     = (const float*)d_in[6];
    float* out = (float*)d_out;
    float* ws  = (float*)d_ws;

    geo_precompute<<<1, 64, 0, stream>>>(cm, alpha, gamma_, centers, geo, ws);

    const int total = NB * HW;                 // 131072 pixels
    geo_main<<<total / PXB, 256, 0, stream>>>(feats, ws, out);
}

// Round 5
// 56.078 us; speedup vs baseline: 2.8982x; 2.8982x over previous
//
#include <hip/hip_runtime.h>
#include <hip/hip_bf16.h>
#include <math.h>

// Problem constants (fixed by setup_inputs)
#define NB 8
#define NC 256
#define HW 16384          // 128*128
#define NP 64
#define PXB 64            // pixels per block (4 waves x 16 px)

typedef __attribute__((ext_vector_type(8))) short bf16x8;
typedef __attribute__((ext_vector_type(4))) float f32x4;

// ws layout: bytes [0, 32768): scaled centers as bf16 [P][C] row-major.
// float-indexed region after that:
#define WS_G2F 8192       // gamma^2 * log2(e), per proto
#define WS_E2F (8192+64)  // log2(alpha') - 0.5*G2*psq, per proto
#define WS_U0F (8192+128)
#define WS_U1F (8192+192)

__device__ __forceinline__ short f2bf_rtne(float v) {
    unsigned u = __builtin_bit_cast(unsigned, v);
    u += 0x7fffu + ((u >> 16) & 1u);
    return (short)(u >> 16);
}

__global__ __launch_bounds__(64) void geo_precompute(
    const float* __restrict__ cm,        // (P,K)
    const float* __restrict__ alpha,     // (P,1)
    const float* __restrict__ gamma_,    // (P,1)
    const float* __restrict__ centers,   // (P,C)
    const float* __restrict__ geo,       // (P,1)
    void* __restrict__ wsv)
{
    ushort* cenb = (ushort*)wsv;
    float*  wsf  = (float*)wsv;
    const int p = threadIdx.x;
    if (p >= NP) return;

    float s = 0.f;
    #pragma unroll
    for (int i = 0; i < NP; ++i) s += geo[i];
    const float scale = 1.0f + 0.1f * tanhf(s * (1.0f / NP));

    float psq = 0.f;
    for (int c = 0; c < NC; ++c) {
        float v = centers[p*NC + c] * scale;
        psq += v * v;                          // fp32 psq (matches reference)
        cenb[p*NC + c] = (ushort)f2bf_rtne(v); // bf16 A-operand
    }

    float b0 = cm[2*p+0]; b0 *= b0;
    float b1 = cm[2*p+1]; b1 *= b1;
    wsf[WS_U0F + p] = b0 / (b0 + b1);
    wsf[WS_U1F + p] = b1 / (b0 + b1);

    const float L2E = 1.4426950408889634f;
    const float al  = 0.99f / (1.f + expf(-alpha[p]));
    const float G2  = gamma_[p] * gamma_[p] * L2E;
    wsf[WS_G2F + p] = G2;
    wsf[WS_E2F + p] = log2f(al) - 0.5f * G2 * psq;
    // s_act = al * exp(-g2 * d) = exp2(E2 + G2*(x.p - 0.5*x_sq))
}

// Block = 256 threads (4 waves), 64 pixels. Wave w owns 16 pixels, computes
// all 64 protos via 4 m-tiles of mfma_f32_16x16x32_bf16 over 8 k-steps.
// No LDS / no barriers in the k-loop (round-4 lesson). s_act exchanged via
// padded LDS, then the proven sequential scan (tid<64).
__global__ __launch_bounds__(256) void geo_main(
    const float* __restrict__ feats,     // (B,C,H,W) fp32
    const void*  __restrict__ wsv,
    float* __restrict__ out)             // (B,3,H,W)
{
    const ushort* __restrict__ cenb = (const ushort*)wsv;
    const float*  __restrict__ wsf  = (const float*)wsv;

    __shared__ float sS[NP][PXB + 2];    // +2 pad: max 2-way bank alias (free)
    __shared__ float sG2[NP], sE2[NP], sU0[NP], sU1[NP];

    const int tid  = threadIdx.x;
    const int lane = tid & 63;
    const int wu   = tid >> 6;           // wave id 0..3
    const int col  = lane & 15;          // A: proto-row within tile / B: pixel
    const int kg   = lane >> 4;          // k-group 0..3 (8 channels each)

    if (tid < NP) {
        sG2[tid] = wsf[WS_G2F + tid];
        sE2[tid] = wsf[WS_E2F + tid];
        sU0[tid] = wsf[WS_U0F + tid];
        sU1[tid] = wsf[WS_U1F + tid];
    }
    __syncthreads();

    const int pix0 = blockIdx.x * PXB;
    const int b    = pix0 >> 14;
    const int hw0  = pix0 & (HW - 1);
    // this lane's pixel: hw0 + wu*16 + col
    const float* __restrict__ fpx = feats + (size_t)b * NC * HW + hw0 + wu*16 + col;

    f32x4 acc0 = {0.f,0.f,0.f,0.f};
    f32x4 acc1 = {0.f,0.f,0.f,0.f};
    f32x4 acc2 = {0.f,0.f,0.f,0.f};
    f32x4 acc3 = {0.f,0.f,0.f,0.f};
    float xsq = 0.f;

    float vB[8], vBn[8];
    #pragma unroll
    for (int j = 0; j < 8; ++j) vB[j] = fpx[(size_t)(kg*8 + j) * HW];

    #pragma unroll 1
    for (int ks = 0; ks < 8; ++ks) {
        // software prefetch of next k-step's B values (covers VMEM latency)
        if (ks < 7) {
            #pragma unroll
            for (int j = 0; j < 8; ++j)
                vBn[j] = fpx[(size_t)((ks+1)*32 + kg*8 + j) * HW];
        }

        // pack current B fragment (bf16 RTNE) + accumulate fp32 x_sq
        bf16x8 bfrag;
        #pragma unroll
        for (int j = 0; j < 8; ++j) {
            bfrag[j] = f2bf_rtne(vB[j]);
            xsq += vB[j] * vB[j];
        }

        // A fragments: 16B rows from bf16 [p][c]; perfectly coalesced, L1-hot
        const int c0 = ks*32 + kg*8;
        const bf16x8 a0 = *(const bf16x8*)&cenb[( 0 + col)*NC + c0];
        const bf16x8 a1 = *(const bf16x8*)&cenb[(16 + col)*NC + c0];
        const bf16x8 a2 = *(const bf16x8*)&cenb[(32 + col)*NC + c0];
        const bf16x8 a3 = *(const bf16x8*)&cenb[(48 + col)*NC + c0];

        acc0 = __builtin_amdgcn_mfma_f32_16x16x32_bf16(a0, bfrag, acc0, 0, 0, 0);
        acc1 = __builtin_amdgcn_mfma_f32_16x16x32_bf16(a1, bfrag, acc1, 0, 0, 0);
        acc2 = __builtin_amdgcn_mfma_f32_16x16x32_bf16(a2, bfrag, acc2, 0, 0, 0);
        acc3 = __builtin_amdgcn_mfma_f32_16x16x32_bf16(a3, bfrag, acc3, 0, 0, 0);

        if (ks < 7) {
            #pragma unroll
            for (int j = 0; j < 8; ++j) vB[j] = vBn[j];
        }
    }

    // full x_sq for this lane's pixel: reduce over the 4 k-groups
    xsq += __shfl_xor(xsq, 16);
    xsq += __shfl_xor(xsq, 32);
    const float xh = 0.5f * xsq;

    // s_act: lane holds protos p = m*16 + kg*4 + r for pixel (wu*16+col)
    const int wpx = wu*16 + col;
    #define EPI(M, ACC)                                                       \
    {                                                                         \
        _Pragma("unroll")                                                     \
        for (int r = 0; r < 4; ++r) {                                         \
            const int p = (M)*16 + kg*4 + r;                                  \
            sS[p][wpx] = exp2f(sE2[p] + sG2[p] * (ACC[r] - xh));              \
        }                                                                     \
    }
    EPI(0, acc0) EPI(1, acc1) EPI(2, acc2) EPI(3, acc3)
    #undef EPI
    __syncthreads();

    // sequential evidential scan per pixel (64 steps, registers only)
    if (tid < PXB) {
        float ms0 = 0.f, ms1 = 0.f, mt = 1.f;
        #pragma unroll
        for (int p = 0; p < NP; ++p) {
            const float s   = sS[p][tid];
            const float mth = 1.f - s;
            const float m0  = s * sU0[p];
            const float m1  = s * sU1[p];
            ms0 = ms0 * (m0 + mth) + m0 * mt;
            ms1 = ms1 * (m1 + mth) + m1 * mt;
            mt *= mth;
        }
        const float inv = 1.f / (ms0 + ms1 + mt + 1e-12f);
        float* __restrict__ op = out + (size_t)b * 3 * HW + hw0 + tid;
        op[0*HW] = ms0 * inv;
        op[1*HW] = ms1 * inv;
        op[2*HW] = mt  * inv;
    }
}

extern "C" void kernel_launch(void* const* d_in, const int* in_sizes, int n_in,
                              void* d_out, int out_size, void* d_ws, size_t ws_size,
                              hipStream_t stream) {
    const float* feats   = (const float*)d_in[0];
    // d_in[1] = geo_context (unused by reference)
    const float* cm      = (const float*)d_in[2];
    const float* alpha   = (const float*)d_in[3];
    const float* gamma_  = (const float*)d_in[4];
    const float* centers = (const float*)d_in[5];
    const float* geo     = (const float*)d_in[6];
    float* out = (float*)d_out;

    geo_precompute<<<1, 64, 0, stream>>>(cm, alpha, gamma_, centers, geo, d_ws);

    const int total = NB * HW;                 // 131072 pixels
    geo_main<<<total / PXB, 256, 0, stream>>>(feats, d_ws, out);
}

// Round 7
// 48.454 us; speedup vs baseline: 3.3542x; 1.1573x over previous
//
#include <hip/hip_runtime.h>
#include <hip/hip_bf16.h>
#include <math.h>

// Problem constants (fixed by setup_inputs)
#define NB 8
#define NC 256
#define HW 16384          // 128*128
#define NP 64
#define PXB 64            // pixels per block (4 waves x 16 px)

typedef __attribute__((ext_vector_type(8))) short bf16x8;
typedef __attribute__((ext_vector_type(4))) int   i32x4;
typedef __attribute__((ext_vector_type(4))) float f32x4;

// ws layout: bytes [0, 32768): scaled centers as bf16 [P][C] row-major.
// float-indexed region after that:
#define WS_G2F 8192       // gamma^2 * log2(e), per proto
#define WS_E2F (8192+64)  // log2(alpha') - 0.5*G2*psq, per proto
#define WS_U0F (8192+128)
#define WS_U1F (8192+192)

__device__ __forceinline__ ushort f2bf_rtne(float v) {
    unsigned u = __builtin_bit_cast(unsigned, v);
    u += 0x7fffu + ((u >> 16) & 1u);
    return (ushort)(u >> 16);
}

// Parallel precompute: block p (64 blocks), 64 threads; thread t owns 4 channels.
__global__ __launch_bounds__(64) void geo_precompute(
    const float* __restrict__ cm,        // (P,K)
    const float* __restrict__ alpha,     // (P,1)
    const float* __restrict__ gamma_,    // (P,1)
    const float* __restrict__ centers,   // (P,C)
    const float* __restrict__ geo,       // (P,1)
    void* __restrict__ wsv)
{
    ushort* cenb = (ushort*)wsv;
    float*  wsf  = (float*)wsv;
    const int p = blockIdx.x;
    const int t = threadIdx.x;

    // mean(geo) via wave butterfly (all lanes end with the sum)
    float s = geo[t];
    #pragma unroll
    for (int d = 1; d < 64; d <<= 1) s += __shfl_xor(s, d);
    const float scale = 1.0f + 0.1f * tanhf(s * (1.0f / NP));

    // 4 channels per thread: scale, psq partial, bf16 store
    const float4 cv = *(const float4*)&centers[p*NC + t*4];
    const float c0 = cv.x * scale, c1 = cv.y * scale;
    const float c2 = cv.z * scale, c3 = cv.w * scale;
    float psq = c0*c0 + c1*c1 + c2*c2 + c3*c3;

    ushort4 ub;
    ub.x = f2bf_rtne(c0); ub.y = f2bf_rtne(c1);
    ub.z = f2bf_rtne(c2); ub.w = f2bf_rtne(c3);
    *(ushort4*)&cenb[p*NC + t*4] = ub;

    #pragma unroll
    for (int d = 1; d < 64; d <<= 1) psq += __shfl_xor(psq, d);

    if (t == 0) {
        float b0 = cm[2*p+0]; b0 *= b0;
        float b1 = cm[2*p+1]; b1 *= b1;
        wsf[WS_U0F + p] = b0 / (b0 + b1);
        wsf[WS_U1F + p] = b1 / (b0 + b1);

        const float L2E = 1.4426950408889634f;
        const float al  = 0.99f / (1.f + expf(-alpha[p]));
        const float G2  = gamma_[p] * gamma_[p] * L2E;
        wsf[WS_G2F + p] = G2;
        wsf[WS_E2F + p] = log2f(al) - 0.5f * G2 * psq;
        // s_act = exp2(E2 + G2*(x.p - 0.5*x_sq))
    }
}

__device__ __forceinline__ bf16x8 pack_bf8(const float* f) {
    i32x4 bi;
    #pragma unroll
    for (int j = 0; j < 4; ++j) {
        __hip_bfloat162 h = __float22bfloat162_rn(make_float2(f[2*j], f[2*j+1]));
        int r;
        __builtin_memcpy(&r, &h, 4);            // bit-move; cvt_pk fusion intact
        bi[j] = r;
    }
    return __builtin_bit_cast(bf16x8, bi);
}

// Block = 256 threads (4 waves), 64 pixels. Wave w owns 16 pixels, computes
// all 64 protos via 4 m-tiles of mfma_f32_16x16x32_bf16 over 8 k-steps.
// No LDS / no barriers in the k-loop. s_act exchanged via padded LDS, then
// the sequential evidential scan (tid<64).
__global__ __launch_bounds__(256) void geo_main(
    const float* __restrict__ feats,     // (B,C,H,W) fp32
    const void*  __restrict__ wsv,
    float* __restrict__ out)             // (B,3,H,W)
{
    const ushort* __restrict__ cenb = (const ushort*)wsv;
    const float*  __restrict__ wsf  = (const float*)wsv;

    __shared__ float sS[NP][PXB + 2];    // +2 pad: max 2-way bank alias (free)
    __shared__ float sG2[NP], sE2[NP], sU0[NP], sU1[NP];

    const int tid  = threadIdx.x;
    const int lane = tid & 63;
    const int wu   = tid >> 6;           // wave id 0..3
    const int col  = lane & 15;          // A: proto-row in tile / B: pixel
    const int kg   = lane >> 4;          // k-group 0..3 (8 channels each)

    if (tid < NP) {
        sG2[tid] = wsf[WS_G2F + tid];
        sE2[tid] = wsf[WS_E2F + tid];
        sU0[tid] = wsf[WS_U0F + tid];
        sU1[tid] = wsf[WS_U1F + tid];
    }
    __syncthreads();

    const int pix0 = blockIdx.x * PXB;
    const int b    = pix0 >> 14;
    const int hw0  = pix0 & (HW - 1);
    const float* __restrict__ fpx = feats + (size_t)b * NC * HW + hw0 + wu*16 + col;

    f32x4 acc0 = {0.f,0.f,0.f,0.f};
    f32x4 acc1 = {0.f,0.f,0.f,0.f};
    f32x4 acc2 = {0.f,0.f,0.f,0.f};
    f32x4 acc3 = {0.f,0.f,0.f,0.f};
    float xsq = 0.f;

    // one MFMA k-step (32 channels): consume buffer F at channel base (KS)*32
    #define KSTEP(F, KS)                                                      \
    {                                                                         \
        _Pragma("unroll")                                                     \
        for (int j = 0; j < 8; ++j) xsq += F[j] * F[j];                       \
        const bf16x8 bfrag = pack_bf8(F);                                     \
        const int c0 = (KS)*32 + kg*8;                                        \
        const bf16x8 a0 = *(const bf16x8*)&cenb[( 0 + col)*NC + c0];          \
        const bf16x8 a1 = *(const bf16x8*)&cenb[(16 + col)*NC + c0];          \
        const bf16x8 a2 = *(const bf16x8*)&cenb[(32 + col)*NC + c0];          \
        const bf16x8 a3 = *(const bf16x8*)&cenb[(48 + col)*NC + c0];          \
        acc0 = __builtin_amdgcn_mfma_f32_16x16x32_bf16(a0, bfrag, acc0, 0,0,0);\
        acc1 = __builtin_amdgcn_mfma_f32_16x16x32_bf16(a1, bfrag, acc1, 0,0,0);\
        acc2 = __builtin_amdgcn_mfma_f32_16x16x32_bf16(a2, bfrag, acc2, 0,0,0);\
        acc3 = __builtin_amdgcn_mfma_f32_16x16x32_bf16(a3, bfrag, acc3, 0,0,0);\
    }

    #define LOADB(F, KS)                                                      \
    {                                                                         \
        _Pragma("unroll")                                                     \
        for (int j = 0; j < 8; ++j)                                           \
            F[j] = fpx[(size_t)((KS)*32 + kg*8 + j) * HW];                    \
    }

    float fA[8], fB[8];
    LOADB(fA, 0)

    #pragma unroll 1
    for (int ks2 = 0; ks2 < 4; ++ks2) {       // 2 k-steps per iteration
        LOADB(fB, 2*ks2 + 1)                  // prefetch odd step
        KSTEP(fA, 2*ks2)
        if (ks2 < 3) LOADB(fA, 2*ks2 + 2)     // prefetch next even step
        KSTEP(fB, 2*ks2 + 1)
    }
    #undef KSTEP
    #undef LOADB

    // full x_sq for this lane's pixel: reduce over the 4 k-groups
    xsq += __shfl_xor(xsq, 16);
    xsq += __shfl_xor(xsq, 32);
    const float xh = 0.5f * xsq;

    // s_act: lane holds protos p = m*16 + kg*4 + r for pixel (wu*16+col)
    const int wpx = wu*16 + col;
    #define EPI(M, ACC)                                                       \
    {                                                                         \
        _Pragma("unroll")                                                     \
        for (int r = 0; r < 4; ++r) {                                         \
            const int p = (M)*16 + kg*4 + r;                                  \
            sS[p][wpx] = exp2f(sE2[p] + sG2[p] * (ACC[r] - xh));              \
        }                                                                     \
    }
    EPI(0, acc0) EPI(1, acc1) EPI(2, acc2) EPI(3, acc3)
    #undef EPI
    __syncthreads();

    // sequential evidential scan per pixel (64 steps, registers only)
    if (tid < PXB) {
        float ms0 = 0.f, ms1 = 0.f, mt = 1.f;
        #pragma unroll
        for (int p = 0; p < NP; ++p) {
            const float s   = sS[p][tid];
            const float mth = 1.f - s;
            const float m0  = s * sU0[p];
            const float m1  = s * sU1[p];
            ms0 = ms0 * (m0 + mth) + m0 * mt;
            ms1 = ms1 * (m1 + mth) + m1 * mt;
            mt *= mth;
        }
        const float inv = 1.f / (ms0 + ms1 + mt + 1e-12f);
        float* __restrict__ op = out + (size_t)b * 3 * HW + hw0 + tid;
        op[0*HW] = ms0 * inv;
        op[1*HW] = ms1 * inv;
        op[2*HW] = mt  * inv;
    }
}

extern "C" void kernel_launch(void* const* d_in, const int* in_sizes, int n_in,
                              void* d_out, int out_size, void* d_ws, size_t ws_size,
                              hipStream_t stream) {
    const float* feats   = (const float*)d_in[0];
    // d_in[1] = geo_context (unused by reference)
    const float* cm      = (const float*)d_in[2];
    const float* alpha   = (const float*)d_in[3];
    const float* gamma_  = (const float*)d_in[4];
    const float* centers = (const float*)d_in[5];
    const float* geo     = (const float*)d_in[6];
    float* out = (float*)d_out;

    geo_precompute<<<NP, 64, 0, stream>>>(cm, alpha, gamma_, centers, geo, d_ws);

    const int total = NB * HW;                 // 131072 pixels
    geo_main<<<total / PXB, 256, 0, stream>>>(feats, d_ws, out);
}

// Round 8
// 42.760 us; speedup vs baseline: 3.8009x; 1.1332x over previous
//
#include <hip/hip_runtime.h>
#include <hip/hip_bf16.h>
#include <math.h>

// Problem constants (fixed by setup_inputs)
#define NB 8
#define NC 256
#define HW 16384          // 128*128
#define NP 64
#define PXW 32            // pixels per wave (2 n-tiles)
#define PXB 128           // pixels per block (4 waves)

typedef __attribute__((ext_vector_type(8))) short bf16x8;
typedef __attribute__((ext_vector_type(4))) int   i32x4;
typedef __attribute__((ext_vector_type(4))) float f32x4;

// ws layout: bytes [0, 32768): scaled centers as bf16 [P][C] row-major.
// float-indexed region after that:
#define WS_G2F 8192       // gamma^2 * log2(e), per proto
#define WS_E2F (8192+64)  // log2(alpha') - 0.5*G2*psq, per proto
#define WS_U0F (8192+128)
#define WS_U1F (8192+192)

__device__ __forceinline__ ushort f2bf_rtne(float v) {
    unsigned u = __builtin_bit_cast(unsigned, v);
    u += 0x7fffu + ((u >> 16) & 1u);
    return (ushort)(u >> 16);
}

// Parallel precompute: block p (64 blocks), 64 threads; thread t owns 4 channels.
__global__ __launch_bounds__(64) void geo_precompute(
    const float* __restrict__ cm,        // (P,K)
    const float* __restrict__ alpha,     // (P,1)
    const float* __restrict__ gamma_,    // (P,1)
    const float* __restrict__ centers,   // (P,C)
    const float* __restrict__ geo,       // (P,1)
    void* __restrict__ wsv)
{
    ushort* cenb = (ushort*)wsv;
    float*  wsf  = (float*)wsv;
    const int p = blockIdx.x;
    const int t = threadIdx.x;

    // mean(geo) via wave butterfly
    float s = geo[t];
    #pragma unroll
    for (int d = 1; d < 64; d <<= 1) s += __shfl_xor(s, d);
    const float scale = 1.0f + 0.1f * tanhf(s * (1.0f / NP));

    const float4 cv = *(const float4*)&centers[p*NC + t*4];
    const float c0 = cv.x * scale, c1 = cv.y * scale;
    const float c2 = cv.z * scale, c3 = cv.w * scale;
    float psq = c0*c0 + c1*c1 + c2*c2 + c3*c3;

    ushort4 ub;
    ub.x = f2bf_rtne(c0); ub.y = f2bf_rtne(c1);
    ub.z = f2bf_rtne(c2); ub.w = f2bf_rtne(c3);
    *(ushort4*)&cenb[p*NC + t*4] = ub;

    #pragma unroll
    for (int d = 1; d < 64; d <<= 1) psq += __shfl_xor(psq, d);

    if (t == 0) {
        float b0 = cm[2*p+0]; b0 *= b0;
        float b1 = cm[2*p+1]; b1 *= b1;
        wsf[WS_U0F + p] = b0 / (b0 + b1);
        wsf[WS_U1F + p] = b1 / (b0 + b1);

        const float L2E = 1.4426950408889634f;
        const float al  = 0.99f / (1.f + expf(-alpha[p]));
        const float G2  = gamma_[p] * gamma_[p] * L2E;
        wsf[WS_G2F + p] = G2;
        wsf[WS_E2F + p] = log2f(al) - 0.5f * G2 * psq;
        // s_act = exp2(E2 + G2*(x.p - 0.5*x_sq))
    }
}

__device__ __forceinline__ bf16x8 pack_bf8(const float* f) {
    i32x4 bi;
    #pragma unroll
    for (int j = 0; j < 4; ++j) {
        __hip_bfloat162 h = __float22bfloat162_rn(make_float2(f[2*j], f[2*j+1]));
        int r;
        __builtin_memcpy(&r, &h, 4);            // bit-move; cvt_pk fusion intact
        bi[j] = r;
    }
    return __builtin_bit_cast(bf16x8, bi);
}

// Block = 256 threads (4 waves), 128 pixels. Wave w owns 32 pixels (2 n-tiles),
// computes all 64 protos: per k-step, 4 A-loads feed 8 MFMAs (A-traffic
// amortized 2x vs round 7). s_act exchanged via fp16 LDS (17 KB), then the
// sequential evidential scan on tid<128.
__global__ __launch_bounds__(256) void geo_main(
    const float* __restrict__ feats,     // (B,C,H,W) fp32
    const void*  __restrict__ wsv,
    float* __restrict__ out)             // (B,3,H,W)
{
    const ushort* __restrict__ cenb = (const ushort*)wsv;
    const float*  __restrict__ wsf  = (const float*)wsv;

    __shared__ _Float16 sSh[NP][PXB + 4];  // fp16 s_act, padded stride
    __shared__ float sG2[NP], sE2[NP], sU0[NP], sU1[NP];

    const int tid  = threadIdx.x;
    const int lane = tid & 63;
    const int wu   = tid >> 6;           // wave id 0..3
    const int col  = lane & 15;          // pixel-in-tile / A proto-row
    const int kg   = lane >> 4;          // k-group 0..3 (8 channels each)

    if (tid < NP) {
        sG2[tid] = wsf[WS_G2F + tid];
        sE2[tid] = wsf[WS_E2F + tid];
        sU0[tid] = wsf[WS_U0F + tid];
        sU1[tid] = wsf[WS_U1F + tid];
    }
    __syncthreads();

    const int pix0 = blockIdx.x * PXB;
    const int b    = pix0 >> 14;
    const int hw0  = pix0 & (HW - 1);
    const float* __restrict__ fpx0 = feats + (size_t)b * NC * HW + hw0 + wu*PXW + col;
    const float* __restrict__ fpx1 = fpx0 + 16;

    f32x4 accA0 = {0,0,0,0}, accA1 = {0,0,0,0}, accA2 = {0,0,0,0}, accA3 = {0,0,0,0};
    f32x4 accB0 = {0,0,0,0}, accB1 = {0,0,0,0}, accB2 = {0,0,0,0}, accB3 = {0,0,0,0};
    float xsq0 = 0.f, xsq1 = 0.f;

    // one MFMA k-step (32 channels, both pixel groups)
    #define KSTEP(F0, F1, KS)                                                 \
    {                                                                         \
        _Pragma("unroll")                                                     \
        for (int j = 0; j < 8; ++j) { xsq0 += F0[j]*F0[j]; xsq1 += F1[j]*F1[j]; } \
        const bf16x8 bf0 = pack_bf8(F0);                                      \
        const bf16x8 bf1 = pack_bf8(F1);                                      \
        const int c0 = (KS)*32 + kg*8;                                        \
        const bf16x8 a0 = *(const bf16x8*)&cenb[( 0 + col)*NC + c0];          \
        const bf16x8 a1 = *(const bf16x8*)&cenb[(16 + col)*NC + c0];          \
        const bf16x8 a2 = *(const bf16x8*)&cenb[(32 + col)*NC + c0];          \
        const bf16x8 a3 = *(const bf16x8*)&cenb[(48 + col)*NC + c0];          \
        accA0 = __builtin_amdgcn_mfma_f32_16x16x32_bf16(a0, bf0, accA0, 0,0,0);\
        accB0 = __builtin_amdgcn_mfma_f32_16x16x32_bf16(a0, bf1, accB0, 0,0,0);\
        accA1 = __builtin_amdgcn_mfma_f32_16x16x32_bf16(a1, bf0, accA1, 0,0,0);\
        accB1 = __builtin_amdgcn_mfma_f32_16x16x32_bf16(a1, bf1, accB1, 0,0,0);\
        accA2 = __builtin_amdgcn_mfma_f32_16x16x32_bf16(a2, bf0, accA2, 0,0,0);\
        accB2 = __builtin_amdgcn_mfma_f32_16x16x32_bf16(a2, bf1, accB2, 0,0,0);\
        accA3 = __builtin_amdgcn_mfma_f32_16x16x32_bf16(a3, bf0, accA3, 0,0,0);\
        accB3 = __builtin_amdgcn_mfma_f32_16x16x32_bf16(a3, bf1, accB3, 0,0,0);\
    }

    #define LOADB(F0, F1, KS)                                                 \
    {                                                                         \
        _Pragma("unroll")                                                     \
        for (int j = 0; j < 8; ++j) {                                         \
            F0[j] = fpx0[(size_t)((KS)*32 + kg*8 + j) * HW];                  \
            F1[j] = fpx1[(size_t)((KS)*32 + kg*8 + j) * HW];                  \
        }                                                                     \
    }

    float eA0[8], eA1[8], eB0[8], eB1[8];
    LOADB(eA0, eA1, 0)

    #pragma unroll 1
    for (int ks2 = 0; ks2 < 4; ++ks2) {       // 2 k-steps per iteration
        LOADB(eB0, eB1, 2*ks2 + 1)
        KSTEP(eA0, eA1, 2*ks2)
        if (ks2 < 3) LOADB(eA0, eA1, 2*ks2 + 2)
        KSTEP(eB0, eB1, 2*ks2 + 1)
    }
    #undef KSTEP
    #undef LOADB

    // full x_sq per pixel: reduce over the 4 k-groups
    xsq0 += __shfl_xor(xsq0, 16); xsq0 += __shfl_xor(xsq0, 32);
    xsq1 += __shfl_xor(xsq1, 16); xsq1 += __shfl_xor(xsq1, 32);
    const float xh0 = 0.5f * xsq0;
    const float xh1 = 0.5f * xsq1;

    // s_act: lane holds protos p = m*16 + kg*4 + r for pixels wpx0, wpx1
    const int wpx0 = wu*PXW + col;
    const int wpx1 = wpx0 + 16;
    #define EPI(M, ACC, ACCB)                                                 \
    {                                                                         \
        _Pragma("unroll")                                                     \
        for (int r = 0; r < 4; ++r) {                                         \
            const int p = (M)*16 + kg*4 + r;                                  \
            sSh[p][wpx0] = (_Float16)exp2f(sE2[p] + sG2[p] * (ACC[r]  - xh0));\
            sSh[p][wpx1] = (_Float16)exp2f(sE2[p] + sG2[p] * (ACCB[r] - xh1));\
        }                                                                     \
    }
    EPI(0, accA0, accB0) EPI(1, accA1, accB1)
    EPI(2, accA2, accB2) EPI(3, accA3, accB3)
    #undef EPI
    __syncthreads();

    // sequential evidential scan per pixel (64 steps, registers only)
    if (tid < PXB) {
        float ms0 = 0.f, ms1 = 0.f, mt = 1.f;
        #pragma unroll
        for (int p = 0; p < NP; ++p) {
            const float s   = (float)sSh[p][tid];
            const float mth = 1.f - s;
            const float m0  = s * sU0[p];
            const float m1  = s * sU1[p];
            ms0 = ms0 * (m0 + mth) + m0 * mt;
            ms1 = ms1 * (m1 + mth) + m1 * mt;
            mt *= mth;
        }
        const float inv = 1.f / (ms0 + ms1 + mt + 1e-12f);
        float* __restrict__ op = out + (size_t)b * 3 * HW + hw0 + tid;
        op[0*HW] = ms0 * inv;
        op[1*HW] = ms1 * inv;
        op[2*HW] = mt  * inv;
    }
}

extern "C" void kernel_launch(void* const* d_in, const int* in_sizes, int n_in,
                              void* d_out, int out_size, void* d_ws, size_t ws_size,
                              hipStream_t stream) {
    const float* feats   = (const float*)d_in[0];
    // d_in[1] = geo_context (unused by reference)
    const float* cm      = (const float*)d_in[2];
    const float* alpha   = (const float*)d_in[3];
    const float* gamma_  = (const float*)d_in[4];
    const float* centers = (const float*)d_in[5];
    const float* geo     = (const float*)d_in[6];
    float* out = (float*)d_out;

    geo_precompute<<<NP, 64, 0, stream>>>(cm, alpha, gamma_, centers, geo, d_ws);

    const int total = NB * HW;                 // 131072 pixels
    geo_main<<<total / PXB, 256, 0, stream>>>(feats, d_ws, out);
}

// Round 9
// 36.118 us; speedup vs baseline: 4.4998x; 1.1839x over previous
//
#include <hip/hip_runtime.h>
#include <hip/hip_bf16.h>
#include <math.h>

// Problem constants (fixed by setup_inputs)
#define NB 8
#define NC 256
#define HW 16384          // 128*128
#define NP 64
#define PXW 32            // pixels per wave (2 n-tiles)
#define PXB 128           // pixels per block (4 waves)

typedef __attribute__((ext_vector_type(8))) short bf16x8;
typedef __attribute__((ext_vector_type(4))) int   i32x4;
typedef __attribute__((ext_vector_type(4))) float f32x4;

// ws layout: bytes [0, 32768): scaled centers as bf16, XOR-SWIZZLED:
//   element (p, c) lives at byte ((p*512 + c*2) ^ ((p&7)<<4)).
// This image is block-copied linearly into LDS and read back with the same
// swizzle -> conflict-free ds_read_b128 column reads.
// float-indexed region after that:
#define WS_G2F 8192       // gamma^2 * log2(e), per proto
#define WS_E2F (8192+64)  // log2(alpha') - 0.5*G2*psq, per proto
#define WS_U0F (8192+128)
#define WS_U1F (8192+192)

__device__ __forceinline__ ushort f2bf_rtne(float v) {
    unsigned u = __builtin_bit_cast(unsigned, v);
    u += 0x7fffu + ((u >> 16) & 1u);
    return (ushort)(u >> 16);
}

// Parallel precompute: block p (64 blocks), 64 threads; thread t owns 4 channels.
__global__ __launch_bounds__(64) void geo_precompute(
    const float* __restrict__ cm,        // (P,K)
    const float* __restrict__ alpha,     // (P,1)
    const float* __restrict__ gamma_,    // (P,1)
    const float* __restrict__ centers,   // (P,C)
    const float* __restrict__ geo,       // (P,1)
    void* __restrict__ wsv)
{
    char*  cenb = (char*)wsv;
    float* wsf  = (float*)wsv;
    const int p = blockIdx.x;
    const int t = threadIdx.x;

    // mean(geo) via wave butterfly
    float s = geo[t];
    #pragma unroll
    for (int d = 1; d < 64; d <<= 1) s += __shfl_xor(s, d);
    const float scale = 1.0f + 0.1f * tanhf(s * (1.0f / NP));

    const float4 cv = *(const float4*)&centers[p*NC + t*4];
    const float c0 = cv.x * scale, c1 = cv.y * scale;
    const float c2 = cv.z * scale, c3 = cv.w * scale;
    float psq = c0*c0 + c1*c1 + c2*c2 + c3*c3;

    ushort4 ub;
    ub.x = f2bf_rtne(c0); ub.y = f2bf_rtne(c1);
    ub.z = f2bf_rtne(c2); ub.w = f2bf_rtne(c3);
    // swizzled store: byte = (p*512 + t*8) ^ ((p&7)<<4); bit3 (t*8) untouched
    *(ushort4*)(cenb + ((p*512 + t*8) ^ ((p & 7) << 4))) = ub;

    #pragma unroll
    for (int d = 1; d < 64; d <<= 1) psq += __shfl_xor(psq, d);

    if (t == 0) {
        float b0 = cm[2*p+0]; b0 *= b0;
        float b1 = cm[2*p+1]; b1 *= b1;
        wsf[WS_U0F + p] = b0 / (b0 + b1);
        wsf[WS_U1F + p] = b1 / (b0 + b1);

        const float L2E = 1.4426950408889634f;
        const float al  = 0.99f / (1.f + expf(-alpha[p]));
        const float G2  = gamma_[p] * gamma_[p] * L2E;
        wsf[WS_G2F + p] = G2;
        wsf[WS_E2F + p] = log2f(al) - 0.5f * G2 * psq;
        // s_act = exp2(E2 + G2*(x.p - 0.5*x_sq))
    }
}

__device__ __forceinline__ bf16x8 pack_bf8(const float* f) {
    i32x4 bi;
    #pragma unroll
    for (int j = 0; j < 4; ++j) {
        __hip_bfloat162 h = __float22bfloat162_rn(make_float2(f[2*j], f[2*j+1]));
        int r;
        __builtin_memcpy(&r, &h, 4);            // bit-move; cvt_pk fusion intact
        bi[j] = r;
    }
    return __builtin_bit_cast(bf16x8, bi);
}

// Block = 256 threads (4 waves), 128 pixels. A (centers) staged once into LDS
// (XOR-swizzled, conflict-free ds_read_b128) -> L1 path left entirely to the
// B (feats) stream. s_act exchange buffer overlays the A buffer (barrier-
// separated), keeping LDS ~34 KB -> 4 blocks/CU (grid-limited, unchanged).
__global__ __launch_bounds__(256) void geo_main(
    const float* __restrict__ feats,     // (B,C,H,W) fp32
    const void*  __restrict__ wsv,
    float* __restrict__ out)             // (B,3,H,W)
{
    const float* __restrict__ wsf = (const float*)wsv;

    __shared__ __align__(16) char sAbuf[NP*512];   // 32 KB: swizzled A image
    __shared__ float sG2[NP], sE2[NP], sU0[NP], sU1[NP];
    _Float16 (*sSh)[PXB + 4] = (_Float16 (*)[PXB + 4])sAbuf;  // overlay (16.9 KB)

    const int tid  = threadIdx.x;
    const int lane = tid & 63;
    const int wu   = tid >> 6;           // wave id 0..3
    const int col  = lane & 15;          // pixel-in-tile / A proto-row
    const int kg   = lane >> 4;          // k-group 0..3 (8 channels each)
    const int swz  = (col & 7) << 4;     // T2 swizzle (p&7 == col&7 for p=m*16+col)

    // stage swizzled A image: 32 KB linear copy, 8 x float4 per thread
    {
        const float4* __restrict__ src = (const float4*)wsv;
        float4* dst = (float4*)sAbuf;
        #pragma unroll
        for (int i = 0; i < 8; ++i) dst[tid + 256*i] = src[tid + 256*i];
    }
    if (tid < NP) {
        sG2[tid] = wsf[WS_G2F + tid];
        sE2[tid] = wsf[WS_E2F + tid];
        sU0[tid] = wsf[WS_U0F + tid];
        sU1[tid] = wsf[WS_U1F + tid];
    }
    __syncthreads();

    const int pix0 = blockIdx.x * PXB;
    const int b    = pix0 >> 14;
    const int hw0  = pix0 & (HW - 1);
    const float* __restrict__ fpx0 = feats + (size_t)b * NC * HW + hw0 + wu*PXW + col;
    const float* __restrict__ fpx1 = fpx0 + 16;

    f32x4 accA0 = {0,0,0,0}, accA1 = {0,0,0,0}, accA2 = {0,0,0,0}, accA3 = {0,0,0,0};
    f32x4 accB0 = {0,0,0,0}, accB1 = {0,0,0,0}, accB2 = {0,0,0,0}, accB3 = {0,0,0,0};
    float xsq0 = 0.f, xsq1 = 0.f;

    // one MFMA k-step (32 channels, both pixel groups); A from swizzled LDS
    #define KSTEP(F0, F1, KS)                                                 \
    {                                                                         \
        _Pragma("unroll")                                                     \
        for (int j = 0; j < 8; ++j) { xsq0 += F0[j]*F0[j]; xsq1 += F1[j]*F1[j]; } \
        const bf16x8 bf0 = pack_bf8(F0);                                      \
        const bf16x8 bf1 = pack_bf8(F1);                                      \
        const char* abase = sAbuf + ((col*512 + (KS)*64 + kg*16) ^ swz);      \
        const bf16x8 a0 = *(const bf16x8*)(abase + 0*8192);                   \
        const bf16x8 a1 = *(const bf16x8*)(abase + 1*8192);                   \
        const bf16x8 a2 = *(const bf16x8*)(abase + 2*8192);                   \
        const bf16x8 a3 = *(const bf16x8*)(abase + 3*8192);                   \
        accA0 = __builtin_amdgcn_mfma_f32_16x16x32_bf16(a0, bf0, accA0, 0,0,0);\
        accB0 = __builtin_amdgcn_mfma_f32_16x16x32_bf16(a0, bf1, accB0, 0,0,0);\
        accA1 = __builtin_amdgcn_mfma_f32_16x16x32_bf16(a1, bf0, accA1, 0,0,0);\
        accB1 = __builtin_amdgcn_mfma_f32_16x16x32_bf16(a1, bf1, accB1, 0,0,0);\
        accA2 = __builtin_amdgcn_mfma_f32_16x16x32_bf16(a2, bf0, accA2, 0,0,0);\
        accB2 = __builtin_amdgcn_mfma_f32_16x16x32_bf16(a2, bf1, accB2, 0,0,0);\
        accA3 = __builtin_amdgcn_mfma_f32_16x16x32_bf16(a3, bf0, accA3, 0,0,0);\
        accB3 = __builtin_amdgcn_mfma_f32_16x16x32_bf16(a3, bf1, accB3, 0,0,0);\
    }

    #define LOADB(F0, F1, KS)                                                 \
    {                                                                         \
        _Pragma("unroll")                                                     \
        for (int j = 0; j < 8; ++j) {                                         \
            F0[j] = fpx0[(size_t)((KS)*32 + kg*8 + j) * HW];                  \
            F1[j] = fpx1[(size_t)((KS)*32 + kg*8 + j) * HW];                  \
        }                                                                     \
    }

    float eA0[8], eA1[8], eB0[8], eB1[8];
    LOADB(eA0, eA1, 0)

    #pragma unroll 1
    for (int ks2 = 0; ks2 < 4; ++ks2) {       // 2 k-steps per iteration
        LOADB(eB0, eB1, 2*ks2 + 1)
        KSTEP(eA0, eA1, 2*ks2)
        if (ks2 < 3) LOADB(eA0, eA1, 2*ks2 + 2)
        KSTEP(eB0, eB1, 2*ks2 + 1)
    }
    #undef KSTEP
    #undef LOADB

    // full x_sq per pixel: reduce over the 4 k-groups
    xsq0 += __shfl_xor(xsq0, 16); xsq0 += __shfl_xor(xsq0, 32);
    xsq1 += __shfl_xor(xsq1, 16); xsq1 += __shfl_xor(xsq1, 32);
    const float xh0 = 0.5f * xsq0;
    const float xh1 = 0.5f * xsq1;

    __syncthreads();   // all waves done reading A -> safe to overlay sSh

    // s_act: lane holds protos p = m*16 + kg*4 + r for pixels wpx0, wpx1
    const int wpx0 = wu*PXW + col;
    const int wpx1 = wpx0 + 16;
    #define EPI(M, ACC, ACCB)                                                 \
    {                                                                         \
        _Pragma("unroll")                                                     \
        for (int r = 0; r < 4; ++r) {                                         \
            const int p = (M)*16 + kg*4 + r;                                  \
            sSh[p][wpx0] = (_Float16)exp2f(sE2[p] + sG2[p] * (ACC[r]  - xh0));\
            sSh[p][wpx1] = (_Float16)exp2f(sE2[p] + sG2[p] * (ACCB[r] - xh1));\
        }                                                                     \
    }
    EPI(0, accA0, accB0) EPI(1, accA1, accB1)
    EPI(2, accA2, accB2) EPI(3, accA3, accB3)
    #undef EPI
    __syncthreads();

    // sequential evidential scan per pixel (64 steps, registers only)
    if (tid < PXB) {
        float ms0 = 0.f, ms1 = 0.f, mt = 1.f;
        #pragma unroll
        for (int p = 0; p < NP; ++p) {
            const float s   = (float)sSh[p][tid];
            const float mth = 1.f - s;
            const float m0  = s * sU0[p];
            const float m1  = s * sU1[p];
            ms0 = ms0 * (m0 + mth) + m0 * mt;
            ms1 = ms1 * (m1 + mth) + m1 * mt;
            mt *= mth;
        }
        const float inv = 1.f / (ms0 + ms1 + mt + 1e-12f);
        float* __restrict__ op = out + (size_t)b * 3 * HW + hw0 + tid;
        op[0*HW] = ms0 * inv;
        op[1*HW] = ms1 * inv;
        op[2*HW] = mt  * inv;
    }
}

extern "C" void kernel_launch(void* const* d_in, const int* in_sizes, int n_in,
                              void* d_out, int out_size, void* d_ws, size_t ws_size,
                              hipStream_t stream) {
    const float* feats   = (const float*)d_in[0];
    // d_in[1] = geo_context (unused by reference)
    const float* cm      = (const float*)d_in[2];
    const float* alpha   = (const float*)d_in[3];
    const float* gamma_  = (const float*)d_in[4];
    const float* centers = (const float*)d_in[5];
    const float* geo     = (const float*)d_in[6];
    float* out = (float*)d_out;

    geo_precompute<<<NP, 64, 0, stream>>>(cm, alpha, gamma_, centers, geo, d_ws);

    const int total = NB * HW;                 // 131072 pixels
    geo_main<<<total / PXB, 256, 0, stream>>>(feats, d_ws, out);
}

// Round 10
// 33.654 us; speedup vs baseline: 4.8292x; 1.0732x over previous
//
#include <hip/hip_runtime.h>
#include <hip/hip_bf16.h>
#include <math.h>

// Problem constants (fixed by setup_inputs)
#define NB 8
#define NC 256
#define HW 16384          // 128*128
#define NP 64
#define PXW 32            // pixels per wave (2 n-tiles)
#define PXB 128           // pixels per block (4 waves)

typedef __attribute__((ext_vector_type(8))) short bf16x8;
typedef __attribute__((ext_vector_type(4))) int   i32x4;
typedef __attribute__((ext_vector_type(4))) float f32x4;

__device__ __forceinline__ ushort f2bf_rtne(float v) {
    unsigned u = __builtin_bit_cast(unsigned, v);
    u += 0x7fffu + ((u >> 16) & 1u);
    return (ushort)(u >> 16);
}

__device__ __forceinline__ bf16x8 pack_bf8(const float* f) {
    i32x4 bi;
    #pragma unroll
    for (int j = 0; j < 4; ++j) {
        __hip_bfloat162 h = __float22bfloat162_rn(make_float2(f[2*j], f[2*j+1]));
        int r;
        __builtin_memcpy(&r, &h, 4);            // bit-move; cvt_pk fusion intact
        bi[j] = r;
    }
    return __builtin_bit_cast(bf16x8, bi);
}

// Single fused kernel. Block = 256 threads (4 waves), 128 pixels.
// Phase 0: issue first 2 k-steps of B (feats) loads -> in flight.
// Phase 1: A-build — every block scales/converts centers (64 KB, L2-hot)
//          into its own XOR-swizzled LDS image + per-proto constants.
//          This work doubles as latency cover for the B prologue.
// Phase 2: k-loop — 8 MFMA k-steps, A from swizzled LDS (conflict-free
//          ds_read_b128), B via register double-buffer. No barriers.
// Phase 3: epilogue exp2 -> fp16 s_act exchange (overlays A buffer) ->
//          sequential evidential scan (tid<128) -> out.
__global__ __launch_bounds__(256) void geo_fused(
    const float* __restrict__ feats,     // (B,C,H,W) fp32
    const float* __restrict__ cm,        // (P,K)
    const float* __restrict__ alpha,     // (P,1)
    const float* __restrict__ gamma_,    // (P,1)
    const float* __restrict__ centers,   // (P,C)
    const float* __restrict__ geo,       // (P,1)
    float* __restrict__ out)             // (B,3,H,W)
{
    __shared__ __align__(16) char sAbuf[NP*512];   // 32 KB swizzled A image
    __shared__ float sG2[NP], sE2[NP], sU0[NP], sU1[NP];
    _Float16 (*sSh)[PXB + 4] = (_Float16 (*)[PXB + 4])sAbuf;  // overlay

    const int tid  = threadIdx.x;
    const int lane = tid & 63;
    const int wu   = tid >> 6;           // wave id 0..3
    const int col  = lane & 15;          // pixel-in-tile / A proto-row
    const int kg   = lane >> 4;          // k-group 0..3 (8 channels each)
    const int swz  = (col & 7) << 4;     // T2 swizzle

    const int pix0 = blockIdx.x * PXB;
    const int b    = pix0 >> 14;
    const int hw0  = pix0 & (HW - 1);
    const float* __restrict__ fpx0 = feats + (size_t)b * NC * HW + hw0 + wu*PXW + col;
    const float* __restrict__ fpx1 = fpx0 + 16;

    #define LOADB(F0, F1, KS)                                                 \
    {                                                                         \
        _Pragma("unroll")                                                     \
        for (int j = 0; j < 8; ++j) {                                         \
            F0[j] = fpx0[(size_t)((KS)*32 + kg*8 + j) * HW];                  \
            F1[j] = fpx1[(size_t)((KS)*32 + kg*8 + j) * HW];                  \
        }                                                                     \
    }

    // ---- Phase 0: B prologue (32 loads in flight before A-build) ----
    float eA0[8], eA1[8], eB0[8], eB1[8];
    LOADB(eA0, eA1, 0)
    LOADB(eB0, eB1, 1)

    // ---- Phase 1: A-build (covers B latency) ----
    {
        // scale = 1 + 0.1*tanh(mean(geo)); per-wave butterfly (redundant x4)
        float gs = geo[lane];
        #pragma unroll
        for (int d = 1; d < 64; d <<= 1) gs += __shfl_xor(gs, d);
        const float scale = 1.0f + 0.1f * tanhf(gs * (1.0f / NP));

        // thread -> proto p = tid>>2, channel comb cb = tid&3
        // channels c = cb*4 + j*16 + {0..3}: lanes 4k..4k+3 cover one 64B line
        const int p  = tid >> 2;
        const int cb = tid & 3;
        float psq = 0.f;
        #pragma unroll 4
        for (int j = 0; j < 16; ++j) {
            const int c = cb*4 + j*16;
            const float4 cv = *(const float4*)&centers[p*NC + c];
            const float c0 = cv.x * scale, c1 = cv.y * scale;
            const float c2 = cv.z * scale, c3 = cv.w * scale;
            psq += c0*c0 + c1*c1 + c2*c2 + c3*c3;
            ushort4 ub;
            ub.x = f2bf_rtne(c0); ub.y = f2bf_rtne(c1);
            ub.z = f2bf_rtne(c2); ub.w = f2bf_rtne(c3);
            // swizzled store: byte = (p*512 + c*2) ^ ((p&7)<<4)
            *(ushort4*)(sAbuf + ((p*512 + c*2) ^ ((p & 7) << 4))) = ub;
        }
        // full psq: reduce over the 4 threads of this proto
        psq += __shfl_xor(psq, 1);
        psq += __shfl_xor(psq, 2);

        if (cb == 0) {
            float b0 = cm[2*p+0]; b0 *= b0;
            float b1 = cm[2*p+1]; b1 *= b1;
            sU0[p] = b0 / (b0 + b1);
            sU1[p] = b1 / (b0 + b1);
            const float L2E = 1.4426950408889634f;
            const float al  = 0.99f / (1.f + expf(-alpha[p]));
            const float G2  = gamma_[p] * gamma_[p] * L2E;
            sG2[p] = G2;
            sE2[p] = log2f(al) - 0.5f * G2 * psq;
            // s_act = exp2(E2 + G2*(x.p - 0.5*x_sq))
        }
    }
    __syncthreads();

    // ---- Phase 2: MFMA k-loop ----
    f32x4 accA0 = {0,0,0,0}, accA1 = {0,0,0,0}, accA2 = {0,0,0,0}, accA3 = {0,0,0,0};
    f32x4 accB0 = {0,0,0,0}, accB1 = {0,0,0,0}, accB2 = {0,0,0,0}, accB3 = {0,0,0,0};
    float xsq0 = 0.f, xsq1 = 0.f;

    #define KSTEP(F0, F1, KS)                                                 \
    {                                                                         \
        _Pragma("unroll")                                                     \
        for (int j = 0; j < 8; ++j) { xsq0 += F0[j]*F0[j]; xsq1 += F1[j]*F1[j]; } \
        const bf16x8 bf0 = pack_bf8(F0);                                      \
        const bf16x8 bf1 = pack_bf8(F1);                                      \
        const char* abase = sAbuf + ((col*512 + (KS)*64 + kg*16) ^ swz);      \
        const bf16x8 a0 = *(const bf16x8*)(abase + 0*8192);                   \
        const bf16x8 a1 = *(const bf16x8*)(abase + 1*8192);                   \
        const bf16x8 a2 = *(const bf16x8*)(abase + 2*8192);                   \
        const bf16x8 a3 = *(const bf16x8*)(abase + 3*8192);                   \
        accA0 = __builtin_amdgcn_mfma_f32_16x16x32_bf16(a0, bf0, accA0, 0,0,0);\
        accB0 = __builtin_amdgcn_mfma_f32_16x16x32_bf16(a0, bf1, accB0, 0,0,0);\
        accA1 = __builtin_amdgcn_mfma_f32_16x16x32_bf16(a1, bf0, accA1, 0,0,0);\
        accB1 = __builtin_amdgcn_mfma_f32_16x16x32_bf16(a1, bf1, accB1, 0,0,0);\
        accA2 = __builtin_amdgcn_mfma_f32_16x16x32_bf16(a2, bf0, accA2, 0,0,0);\
        accB2 = __builtin_amdgcn_mfma_f32_16x16x32_bf16(a2, bf1, accB2, 0,0,0);\
        accA3 = __builtin_amdgcn_mfma_f32_16x16x32_bf16(a3, bf0, accA3, 0,0,0);\
        accB3 = __builtin_amdgcn_mfma_f32_16x16x32_bf16(a3, bf1, accB3, 0,0,0);\
    }

    #pragma unroll 1
    for (int ks2 = 0; ks2 < 4; ++ks2) {       // 2 k-steps per iteration
        KSTEP(eA0, eA1, 2*ks2)
        if (ks2 < 3) LOADB(eA0, eA1, 2*ks2 + 2)
        KSTEP(eB0, eB1, 2*ks2 + 1)
        if (ks2 < 3) LOADB(eB0, eB1, 2*ks2 + 3)
    }
    #undef KSTEP
    #undef LOADB

    // full x_sq per pixel: reduce over the 4 k-groups
    xsq0 += __shfl_xor(xsq0, 16); xsq0 += __shfl_xor(xsq0, 32);
    xsq1 += __shfl_xor(xsq1, 16); xsq1 += __shfl_xor(xsq1, 32);
    const float xh0 = 0.5f * xsq0;
    const float xh1 = 0.5f * xsq1;

    __syncthreads();   // all waves done reading A -> safe to overlay sSh

    // ---- Phase 3: s_act exchange + evidential scan ----
    const int wpx0 = wu*PXW + col;
    const int wpx1 = wpx0 + 16;
    #define EPI(M, ACC, ACCB)                                                 \
    {                                                                         \
        _Pragma("unroll")                                                     \
        for (int r = 0; r < 4; ++r) {                                         \
            const int p = (M)*16 + kg*4 + r;                                  \
            sSh[p][wpx0] = (_Float16)exp2f(sE2[p] + sG2[p] * (ACC[r]  - xh0));\
            sSh[p][wpx1] = (_Float16)exp2f(sE2[p] + sG2[p] * (ACCB[r] - xh1));\
        }                                                                     \
    }
    EPI(0, accA0, accB0) EPI(1, accA1, accB1)
    EPI(2, accA2, accB2) EPI(3, accA3, accB3)
    #undef EPI
    __syncthreads();

    // sequential evidential scan per pixel (64 steps, registers only)
    if (tid < PXB) {
        float ms0 = 0.f, ms1 = 0.f, mt = 1.f;
        #pragma unroll
        for (int p = 0; p < NP; ++p) {
            const float s   = (float)sSh[p][tid];
            const float mth = 1.f - s;
            const float m0  = s * sU0[p];
            const float m1  = s * sU1[p];
            ms0 = ms0 * (m0 + mth) + m0 * mt;
            ms1 = ms1 * (m1 + mth) + m1 * mt;
            mt *= mth;
        }
        const float inv = 1.f / (ms0 + ms1 + mt + 1e-12f);
        float* __restrict__ op = out + (size_t)b * 3 * HW + hw0 + tid;
        op[0*HW] = ms0 * inv;
        op[1*HW] = ms1 * inv;
        op[2*HW] = mt  * inv;
    }
}

extern "C" void kernel_launch(void* const* d_in, const int* in_sizes, int n_in,
                              void* d_out, int out_size, void* d_ws, size_t ws_size,
                              hipStream_t stream) {
    const float* feats   = (const float*)d_in[0];
    // d_in[1] = geo_context (unused by reference)
    const float* cm      = (const float*)d_in[2];
    const float* alpha   = (const float*)d_in[3];
    const float* gamma_  = (const float*)d_in[4];
    const float* centers = (const float*)d_in[5];
    const float* geo     = (const float*)d_in[6];
    float* out = (float*)d_out;

    const int total = NB * HW;                 // 131072 pixels
    geo_fused<<<total / PXB, 256, 0, stream>>>(feats, cm, alpha, gamma_,
                                               centers, geo, out);
}